// Round 2
// baseline (605.761 us; speedup 1.0000x reference)
//
#include <hip/hip_runtime.h>
#include <hip/hip_bf16.h>
#include <stdint.h>

typedef __attribute__((ext_vector_type(8))) short short8;
typedef __attribute__((ext_vector_type(4))) float floatx4;

#define T_DIM 4096
#define D_DIM 128
#define BH_TOT 64
#define LSTR 72                          /* u16 row stride: 9 groups of 8 u16 */
#define KV_FLOATS (128 * 128)            /* per-bh kv elements */
#define SLAB_FLOATS (BH_TOT * KV_FLOATS) /* one chunk slab = 4 MB */

__device__ __forceinline__ unsigned int packbf2(float lo, float hi) {
  union { __hip_bfloat162 b; unsigned int u; } cv;
  cv.b = __float22bfloat162_rn(make_float2(lo, hi));
  return cv.u;
}

__device__ __forceinline__ short8 pack8(float4 a, float4 b) {
  union { short8 s; unsigned int u[4]; } r;
  r.u[0] = packbf2(a.x, a.y);
  r.u[1] = packbf2(a.z, a.w);
  r.u[2] = packbf2(b.x, b.y);
  r.u[3] = packbf2(b.z, b.w);
  return r.s;
}

// ---------------- Phase 1: partial kvT[e][d] = sum_{t in chunk} V[t][e]*K[t][d] ----
// A = V (m=e), B = K (n=d), k = t. Both staged transposed in LDS with a mod-9
// k-group rotation to break the 16-way column-write bank conflict (write lanes
// step rows by 4; gcd with 9 is 1 so banks spread to the b128 floor).
__global__ __launch_bounds__(256, 3)
void kv_phase1(const float* __restrict__ K, const float* __restrict__ V,
               float* __restrict__ dst, int ntiles, int useAtomic) {
  const int bh = blockIdx.y, chunk = blockIdx.x;
  const int tid = threadIdx.x;
  const int lane = tid & 63, wv = tid >> 6;
  const int c = tid & 31, r = tid >> 5;       // c: float4 column group, r: t-subrow
  const int m0 = (wv >> 1) * 64, n0 = (wv & 1) * 64;
  const int q4 = lane >> 4, l15 = lane & 15;

  __shared__ unsigned short Vt[128 * LSTR];
  __shared__ unsigned short Kt[128 * LSTR];

  // precomputed swizzled offsets (u16 units)
  int wo[4];
#pragma unroll
  for (int j = 0; j < 4; ++j) {
    const int row = 4 * c + j;
    wo[j] = row * LSTR + ((r + row) % 9) * 8;
  }
  int roA[4][2], roB[4][2];
#pragma unroll
  for (int tt = 0; tt < 4; ++tt)
#pragma unroll
    for (int ks = 0; ks < 2; ++ks) {
      const int g = 4 * ks + q4;
      const int rowA = m0 + tt * 16 + l15;
      const int rowB = n0 + tt * 16 + l15;
      roA[tt][ks] = rowA * LSTR + ((g + rowA) % 9) * 8;
      roB[tt][ks] = rowB * LSTR + ((g + rowB) % 9) * 8;
    }

  floatx4 acc[4][4];
#pragma unroll
  for (int i = 0; i < 4; ++i)
#pragma unroll
    for (int j = 0; j < 4; ++j) acc[i][j] = (floatx4){0.f, 0.f, 0.f, 0.f};

  const size_t base = ((size_t)bh * T_DIM + (size_t)chunk * (ntiles * 64)) * D_DIM;
  const float* Vp = V + base + 4 * c;
  const float* Kp = K + base + 4 * c;

  float4 ld[2][8];   // [op][t-subrow]; op0=V op1=K
  uint4  pk[2][4];   // packed bf16 columns: [op][j], 8 t-values each

  auto load_tile = [&](int tile) {
    const size_t roff = (size_t)(tile * 64 + 8 * r) * D_DIM;
#pragma unroll
    for (int i = 0; i < 8; ++i) {
      ld[0][i] = *(const float4*)(Vp + roff + (size_t)i * D_DIM);
      ld[1][i] = *(const float4*)(Kp + roff + (size_t)i * D_DIM);
    }
  };
  auto pack_all = [&]() {
#pragma unroll
    for (int op = 0; op < 2; ++op)
#pragma unroll
      for (int j = 0; j < 4; ++j) {
        uint4 v;
        v.x = packbf2(((const float*)&ld[op][0])[j], ((const float*)&ld[op][1])[j]);
        v.y = packbf2(((const float*)&ld[op][2])[j], ((const float*)&ld[op][3])[j]);
        v.z = packbf2(((const float*)&ld[op][4])[j], ((const float*)&ld[op][5])[j]);
        v.w = packbf2(((const float*)&ld[op][6])[j], ((const float*)&ld[op][7])[j]);
        pk[op][j] = v;
      }
  };

  load_tile(0);
  pack_all();

  for (int tile = 0; tile < ntiles; ++tile) {
    if (tile + 1 < ntiles) load_tile(tile + 1);  // prefetch overlaps pack/MFMA
    __syncthreads();
#pragma unroll
    for (int j = 0; j < 4; ++j) {
      *(uint4*)&Vt[wo[j]] = pk[0][j];
      *(uint4*)&Kt[wo[j]] = pk[1][j];
    }
    __syncthreads();
#pragma unroll
    for (int ks = 0; ks < 2; ++ks) {
      short8 af[4], bf[4];
#pragma unroll
      for (int tm = 0; tm < 4; ++tm) af[tm] = *(const short8*)&Vt[roA[tm][ks]];
#pragma unroll
      for (int tn = 0; tn < 4; ++tn) bf[tn] = *(const short8*)&Kt[roB[tn][ks]];
#pragma unroll
      for (int tm = 0; tm < 4; ++tm)
#pragma unroll
        for (int tn = 0; tn < 4; ++tn)
          acc[tm][tn] = __builtin_amdgcn_mfma_f32_16x16x32_bf16(af[tm], bf[tn],
                                                                acc[tm][tn], 0, 0, 0);
    }
    if (tile + 1 < ntiles) pack_all();
  }

  // C/D: col = lane&15 (n=d), row = (lane>>4)*4 + reg (m=e)
  const int col = l15, rb = q4 * 4;
  if (useAtomic) {
    float* dp = dst + (size_t)bh * KV_FLOATS;
#pragma unroll
    for (int tm = 0; tm < 4; ++tm)
#pragma unroll
      for (int tn = 0; tn < 4; ++tn)
#pragma unroll
        for (int rg = 0; rg < 4; ++rg)
          unsafeAtomicAdd(&dp[(m0 + tm * 16 + rb + rg) * 128 + n0 + tn * 16 + col],
                          acc[tm][tn][rg]);
  } else {
    float* dp = dst + ((size_t)chunk * BH_TOT + bh) * KV_FLOATS;
#pragma unroll
    for (int tm = 0; tm < 4; ++tm)
#pragma unroll
      for (int tn = 0; tn < 4; ++tn)
#pragma unroll
        for (int rg = 0; rg < 4; ++rg)
          dp[(m0 + tm * 16 + rb + rg) * 128 + n0 + tn * 16 + col] = acc[tm][tn][rg];
  }
}

// ---------------- Reduce: kv = sum over chunk slabs (fp32) ----------------
__global__ __launch_bounds__(256, 4)
void kv_reduce(const float* __restrict__ slab, float* __restrict__ kv, int nchunk) {
  const int idx = blockIdx.x * 256 + threadIdx.x;  // one float4 per thread
  const float4* p = (const float4*)slab + idx;
  float4 s = p[0];
  for (int c = 1; c < nchunk; ++c) {
    float4 v = p[(size_t)c * (SLAB_FLOATS / 4)];
    s.x += v.x; s.y += v.y; s.z += v.z; s.w += v.w;
  }
  ((float4*)kv)[idx] = s;
}

// ---------------- Phase 2: out[t][e] = sum_d Q[t][d] * kv[e][d] ----------------
// No LDS, no barriers. Both MFMA fragments are 8-consecutive-k per lane, and both
// Q[t][d] and kv[e][d] are d(=k)-contiguous: load fragments straight from global,
// cvt to bf16 in regs. kv (4 MB total) stays L2-hot across its 32 readers per bh.
__global__ __launch_bounds__(256, 3)
void qkv_phase2(const float* __restrict__ Q, const float* __restrict__ kv,
                float* __restrict__ out) {
  const int bh = blockIdx.y;
  const int t0 = blockIdx.x * 128;
  const int tid = threadIdx.x, lane = tid & 63, wv = tid >> 6;
  const int m0 = (wv >> 1) * 64, n0 = (wv & 1) * 64;
  const int q4 = lane >> 4, l15 = lane & 15;

  const float* Qb = Q + ((size_t)bh * T_DIM + t0) * D_DIM;
  const float* Bb = kv + (size_t)bh * KV_FLOATS;

  floatx4 acc[4][4];
#pragma unroll
  for (int i = 0; i < 4; ++i)
#pragma unroll
    for (int j = 0; j < 4; ++j) acc[i][j] = (floatx4){0.f, 0.f, 0.f, 0.f};

#pragma unroll 1
  for (int ks = 0; ks < 4; ++ks) {
    const int koff = 32 * ks + 8 * q4;
    short8 bf[4], af[4];
#pragma unroll
    for (int tn = 0; tn < 4; ++tn) {
      const float* p = Bb + (n0 + tn * 16 + l15) * 128 + koff;
      bf[tn] = pack8(*(const float4*)p, *(const float4*)(p + 4));
    }
#pragma unroll
    for (int tm = 0; tm < 4; ++tm) {
      const float* p = Qb + (size_t)(m0 + tm * 16 + l15) * D_DIM + koff;
      af[tm] = pack8(*(const float4*)p, *(const float4*)(p + 4));
    }
#pragma unroll
    for (int tm = 0; tm < 4; ++tm)
#pragma unroll
      for (int tn = 0; tn < 4; ++tn)
        acc[tm][tn] = __builtin_amdgcn_mfma_f32_16x16x32_bf16(af[tm], bf[tn],
                                                              acc[tm][tn], 0, 0, 0);
  }

  float* op = out + ((size_t)bh * T_DIM + t0) * D_DIM;
  const int col = l15, rb = q4 * 4;
#pragma unroll
  for (int tm = 0; tm < 4; ++tm)
#pragma unroll
    for (int tn = 0; tn < 4; ++tn)
#pragma unroll
      for (int rg = 0; rg < 4; ++rg)
        op[(size_t)(m0 + tm * 16 + rb + rg) * D_DIM + (n0 + tn * 16 + col)] =
            acc[tm][tn][rg];
}

extern "C" void kernel_launch(void* const* d_in, const int* in_sizes, int n_in,
                              void* d_out, int out_size, void* d_ws, size_t ws_size,
                              hipStream_t stream) {
  const float* Q = (const float*)d_in[0];
  const float* K = (const float*)d_in[1];
  const float* V = (const float*)d_in[2];
  float* out = (float*)d_out;
  float* ws = (float*)d_ws;

  const size_t slabBytes = (size_t)SLAB_FLOATS * sizeof(float);  // 4 MB
  int nchunk = 0;
  if (ws_size >= 17 * slabBytes)      nchunk = 16;
  else if (ws_size >= 9 * slabBytes)  nchunk = 8;
  else if (ws_size >= 5 * slabBytes)  nchunk = 4;
  else if (ws_size >= 3 * slabBytes)  nchunk = 2;

  if (nchunk > 0) {
    float* slab = ws;
    float* kvb  = ws + (size_t)nchunk * SLAB_FLOATS;
    kv_phase1<<<dim3(nchunk, BH_TOT), 256, 0, stream>>>(K, V, slab,
                                                        64 / nchunk, 0);
    kv_reduce<<<dim3(SLAB_FLOATS / 4 / 256), 256, 0, stream>>>(slab, kvb, nchunk);
    qkv_phase2<<<dim3(T_DIM / 128, BH_TOT), 256, 0, stream>>>(Q, kvb, out);
  } else {
    // tiny-workspace fallback: atomic accumulation into kv at ws[0]
    float* kvb = ws;
    hipMemsetAsync(kvb, 0, slabBytes, stream);
    kv_phase1<<<dim3(8, BH_TOT), 256, 0, stream>>>(K, V, kvb, 8, 1);
    qkv_phase2<<<dim3(T_DIM / 128, BH_TOT), 256, 0, stream>>>(Q, kvb, out);
  }
}